// Round 1
// baseline (98.288 us; speedup 1.0000x reference)
//
#include <hip/hip_runtime.h>
#include <math.h>
#include <float.h>
#include <limits.h>

#define QPB 32        // queries per block
#define TSTRIPE 8     // threads (stripes) per query
#define TM 2048       // reference points staged per LDS tile
#define KNN 3

__launch_bounds__(256, 2)
__global__ void knn_flow_kernel(const float* __restrict__ pc0,
                                const float* __restrict__ pc1,
                                const float* __restrict__ flow1,
                                const float* __restrict__ pose0,
                                const float* __restrict__ pose1,
                                float* __restrict__ out,
                                int B, int N, int M)
{
    __shared__ float4 tile[TM];
    __shared__ float  md[QPB][TSTRIPE][KNN];
    __shared__ int    mi[QPB][TSTRIPE][KNN];

    const int tid    = threadIdx.x;
    const int qlocal = tid & (QPB - 1);
    const int s      = tid >> 5;           // stripe id 0..7
    const int b      = blockIdx.y;
    const int qg0    = blockIdx.x * QPB + qlocal;
    const bool qvalid = (qg0 < N);
    const int qg     = qvalid ? qg0 : (N - 1);

    // ---- relative pose: pose_0to1 = inv(pose1) @ pose0 (SE3 analytic) ----
    const float* P0 = pose0 + b * 16;
    const float* P1 = pose1 + b * 16;
    float R[3][3], tv[3];
    {
        float dt0 = P0[3]  - P1[3];
        float dt1 = P0[7]  - P1[7];
        float dt2 = P0[11] - P1[11];
        #pragma unroll
        for (int i = 0; i < 3; ++i) {
            float a0 = P1[i], a1 = P1[4 + i], a2 = P1[8 + i]; // column i of R1
            #pragma unroll
            for (int j = 0; j < 3; ++j)
                R[i][j] = fmaf(a2, P0[8 + j], fmaf(a1, P0[4 + j], a0 * P0[j]));
            tv[i] = fmaf(a2, dt2, fmaf(a1, dt1, a0 * dt0));
        }
    }

    // ---- transform this thread's query point ----
    const float px = pc0[(b * N + qg) * 3 + 0];
    const float py = pc0[(b * N + qg) * 3 + 1];
    const float pz = pc0[(b * N + qg) * 3 + 2];
    const float qx = fmaf(R[0][2], pz, fmaf(R[0][1], py, R[0][0] * px)) + tv[0];
    const float qy = fmaf(R[1][2], pz, fmaf(R[1][1], py, R[1][0] * px)) + tv[1];
    const float qz = fmaf(R[2][2], pz, fmaf(R[2][1], py, R[2][0] * px)) + tv[2];
    const float q2 = (qx * qx + qy * qy) + qz * qz;

    float bd0 = FLT_MAX, bd1 = FLT_MAX, bd2 = FLT_MAX;
    int   bi0 = INT_MAX, bi1 = INT_MAX, bi2 = INT_MAX;

    // ---- scan reference points: tiles of TM, stripe-interleaved mod TSTRIPE ----
    for (int tbase = 0; tbase < M; tbase += TM) {
        __syncthreads();
        #pragma unroll
        for (int k = 0; k < TM / 256; ++k) {
            int jl = tid + k * 256;
            int m  = tbase + jl;
            float4 v;
            if (m < M) {
                const float* p = pc1 + (size_t)(b * M + m) * 3;
                float x = p[0], y = p[1], z = p[2];
                v = make_float4(x, y, z, (x * x + y * y) + z * z);
            } else {
                v = make_float4(0.f, 0.f, 0.f, FLT_MAX);
            }
            tile[jl] = v;
        }
        __syncthreads();

        #pragma unroll 4
        for (int i = 0; i < TM / TSTRIPE; ++i) {
            int ml = i * TSTRIPE + s;
            float4 v = tile[ml];
            float cross = fmaf(qz, v.z, fmaf(qy, v.y, qx * v.x));
            float d2 = fmaf(-2.0f, cross, q2 + v.w);  // == (q2+r2) - 2*cross, single rounding
            if (d2 < bd2) {
                int m = tbase + ml;
                if (d2 < bd1) {
                    bd2 = bd1; bi2 = bi1;
                    if (d2 < bd0) { bd1 = bd0; bi1 = bi0; bd0 = d2; bi0 = m; }
                    else          { bd1 = d2;  bi1 = m; }
                } else { bd2 = d2; bi2 = m; }
            }
        }
    }

    // ---- merge the 8 stripes' top-3 lists ----
    md[qlocal][s][0] = bd0; md[qlocal][s][1] = bd1; md[qlocal][s][2] = bd2;
    mi[qlocal][s][0] = bi0; mi[qlocal][s][1] = bi1; mi[qlocal][s][2] = bi2;
    __syncthreads();

    if (tid < QPB && qvalid) {
        float fd0 = FLT_MAX, fd1 = FLT_MAX, fd2 = FLT_MAX;
        int   fi0 = INT_MAX, fi1 = INT_MAX, fi2 = INT_MAX;
        #pragma unroll
        for (int ss = 0; ss < TSTRIPE; ++ss) {
            #pragma unroll
            for (int k = 0; k < KNN; ++k) {
                float d = md[tid][ss][k];
                int   ix = mi[tid][ss][k];
                bool l2 = (d < fd2) || (d == fd2 && ix < fi2);
                if (l2) {
                    bool l1 = (d < fd1) || (d == fd1 && ix < fi1);
                    if (l1) {
                        fd2 = fd1; fi2 = fi1;
                        bool l0 = (d < fd0) || (d == fd0 && ix < fi0);
                        if (l0) { fd1 = fd0; fi1 = fi0; fd0 = d; fi0 = ix; }
                        else    { fd1 = d;   fi1 = ix; }
                    } else { fd2 = d; fi2 = ix; }
                }
            }
        }

        float dd0 = sqrtf(fmaxf(fd0, 0.f));
        float dd1 = sqrtf(fmaxf(fd1, 0.f));
        float dd2 = sqrtf(fmaxf(fd2, 0.f));
        float w0 = 1.0f / (dd0 + 1e-8f);
        float w1 = 1.0f / (dd1 + 1e-8f);
        float w2 = 1.0f / (dd2 + 1e-8f);
        float wsum = (w0 + w1) + w2;
        w0 /= wsum; w1 /= wsum; w2 /= wsum;

        const float* f0 = flow1 + (size_t)(b * M + fi0) * 3;
        const float* f1 = flow1 + (size_t)(b * M + fi1) * 3;
        const float* f2 = flow1 + (size_t)(b * M + fi2) * 3;

        const int ob = (b * N + qg) * 3;
        #pragma unroll
        for (int c = 0; c < 3; ++c) {
            float p0 = w0 * f0[c];
            float p1 = w1 * f1[c];
            float p2 = w2 * f2[c];
            out[ob + c] = (p0 + p1) + p2;
        }
        const int pfbase = B * N * 3 + ob;
        out[pfbase + 0] = qx - px;
        out[pfbase + 1] = qy - py;
        out[pfbase + 2] = qz - pz;
    }
}

extern "C" void kernel_launch(void* const* d_in, const int* in_sizes, int n_in,
                              void* d_out, int out_size, void* d_ws, size_t ws_size,
                              hipStream_t stream) {
    const float* pc0   = (const float*)d_in[0];
    const float* pc1   = (const float*)d_in[1];
    const float* flow1 = (const float*)d_in[2];
    const float* pose0 = (const float*)d_in[3];
    const float* pose1 = (const float*)d_in[4];
    float* out = (float*)d_out;

    const int B = in_sizes[3] / 16;
    const int N = in_sizes[0] / (3 * B);
    const int M = in_sizes[1] / (3 * B);

    dim3 grid((N + QPB - 1) / QPB, B);
    knn_flow_kernel<<<grid, dim3(256), 0, stream>>>(pc0, pc1, flow1, pose0, pose1,
                                                    out, B, N, M);
}